// Round 2
// baseline (456.977 us; speedup 1.0000x reference)
//
#include <hip/hip_runtime.h>

#define T_ 30
#define H_ 41
#define WD_ 2048
#define NSEC 9
#define FM 50
#define WP 502
#define THRESH 23.0f
#define POOLED_SIZE (NSEC * T_ * FM * WP)   // 6,777,000
#define MARGIN 0.08f                        // >= worst-case quant error (~0.066)
#define NFRAG8 9216                         // 9 sec * 64 fm * 4 kk * 4 q

typedef int i32x4 __attribute__((ext_vector_type(4)));
typedef int i32x2 __attribute__((ext_vector_type(2)));

__device__ __forceinline__ unsigned pack_b(int b0, int b1, int b2, int b3) {
    return (unsigned)(b0 & 255) | ((unsigned)(b1 & 255) << 8) |
           ((unsigned)(b2 & 255) << 16) | ((unsigned)(b3 & 255) << 24);
}

// w_q = rn(w*2^11) = wh*2^7 + wm  (wh in [-128,127] arith-shift, wm in [0,127])
// |w| <= ~5 for N(0,1) draws => |wq| <= ~10k, wh fits i8 comfortably.
__device__ __forceinline__ void quant_w2(float w, int& h, int& m) {
    int wq = __float2int_rn(w * 2048.f);
    wq = max(-16383, min(16383, wq));
    h = (wq >> 7) & 255;        // arithmetic shift keeps sign; packed as byte
    m = wq & 127;
}

// ---------------- prep: W -> i8 MFMA fragments (hi/mid) in ws -------------
__global__ __launch_bounds__(256) void prep_kernel(
    const float* __restrict__ Wg, int* __restrict__ wsi,
    uint4* __restrict__ wfh, uint4* __restrict__ wfm)
{
    const int gid = blockIdx.x * 256 + threadIdx.x;
    if (gid < NSEC) wsi[gid] = 0x7fffffff;
    if (gid >= NFRAG8) return;
    const int q   = gid & 3;
    const int kk  = (gid >> 2) & 3;
    const int fm  = (gid >> 4) & 63;
    const int sec = gid >> 10;
    const int t0  = 64 * kk + 16 * q;       // taps t0..t0+15 = k-slots 16q..16q+15 of kk
    unsigned hw[4], mw[4];
#pragma unroll
    for (int g = 0; g < 4; ++g) {
        int hq[4], mq[4];
#pragma unroll
        for (int e = 0; e < 4; ++e) {
            const int t = t0 + 4 * g + e;
            const bool valid = (t < 240) && (fm < FM);
            const int fmC = valid ? fm : 0;
            const int tC  = valid ? t : 0;
            float w = Wg[((size_t)sec * FM + fmC) * 240 + tC];
            if (!valid) w = 0.f;
            quant_w2(w, hq[e], mq[e]);
        }
        hw[g] = pack_b(hq[0], hq[1], hq[2], hq[3]);
        mw[g] = pack_b(mq[0], mq[1], mq[2], mq[3]);
    }
    wfh[gid] = make_uint4(hw[0], hw[1], hw[2], hw[3]);
    wfm[gid] = make_uint4(mw[0], mw[1], mw[2], mw[3]);
}

// build shifted plane S (1..7) from plane 0 by in-LDS byte shift
__device__ __forceinline__ void shift_plane(unsigned char* base, int S, int row, int tq,
                                            int s0, int sh) {
    const unsigned char* p0 = base + row * 176 + 16 * tq;
    uint4 a  = *reinterpret_cast<const uint4*>(p0);
    uint2 b2 = *reinterpret_cast<const uint2*>(p0 + 16);
    const unsigned e0 = s0 ? a.y : a.x;
    const unsigned e1 = s0 ? a.z : a.y;
    const unsigned e2 = s0 ? a.w : a.z;
    const unsigned e3 = s0 ? b2.x : a.w;
    const unsigned e4 = s0 ? b2.y : b2.x;
    uint4 o;
    o.x = (unsigned)((((unsigned long long)e1 << 32) | e0) >> sh);
    o.y = (unsigned)((((unsigned long long)e2 << 32) | e1) >> sh);
    o.z = (unsigned)((((unsigned long long)e3 << 32) | e2) >> sh);
    o.w = (unsigned)((((unsigned long long)e4 << 32) | e3) >> sh);
    *reinterpret_cast<uint4*>(base + S * 1760 + row * 176 + 16 * tq) = o;
}

// ---------------- Kernel A: i8 2x2 split MFMA conv + fire + pool + argmin --
// R11: R10 was register-occupancy-bound (48 B regs + 16 acc -> ~124 combined
// VGPR+AGPR -> 2.5 waves/SIMD, near wave-serial execution). Cut w to 2 planes
// (14-bit, scale 2^11): exact 2x2 product = 4 MFMAs/kk (16/ft-res, -33%),
// B regs 48->32, acc 16->12, simpler recombine. launch_bounds(256,5) = the
// LDS ceiling (5 blocks x 30.2KB). Staging layout byte-identical to R10.
// Error bound 2^-15*Sum|w| + 2^-12*Sum(x) ~= 0.066 < MARGIN 0.08; integer
// path exact; borderline pots repaired with fp32 recompute.
template <bool PRE>
__global__ __launch_bounds__(256, 5) void conv_pool_kernel(
    const float* __restrict__ x, const float* __restrict__ Wg,
    const uint4* __restrict__ wfh, const uint4* __restrict__ wfm,
    float* __restrict__ out, int* __restrict__ keys)
{
    __shared__ __align__(16) unsigned char xh8[8][10][176];   // 13.75 KB
    __shared__ __align__(16) unsigned char xl8[8][10][176];   // 13.75 KB
    __shared__ unsigned lmask[4][64];
    __shared__ int red[256];

    const int b       = blockIdx.x;
    const int coltile = b & 15;
    const int tt      = (b >> 4) % T_;
    const int sec     = b / 480;
    const int w0      = coltile * 128;     // pot-col base
    const int rowbase = 4 * sec;
    const int tid     = threadIdx.x;

    // ---- pass 1: quantize x rows into plane 0 (hi/lo i8) ----
    if (tid < 110) {
        const int row = tid / 11, tq = tid % 11;
        const int grow = min(rowbase + row, H_ - 1);
        const int gc0 = w0 + 16 * tq;
        const float* xp = x + ((size_t)tt * H_ + grow) * WD_;
        unsigned hw[4], lw[4];
#pragma unroll
        for (int g = 0; g < 4; ++g) {
            const int gc = gc0 + 4 * g;
            float4 v;
            if (gc + 3 < WD_) v = *reinterpret_cast<const float4*>(xp + gc);
            else { v.x = v.y = v.z = v.w = 0.f; }
            float f[4] = {v.x, v.y, v.z, v.w};
            int hq[4], lq[4];
#pragma unroll
            for (int e = 0; e < 4; ++e) {
                int qv = __float2int_rn(f[e] * 16384.f);
                qv = min(qv, 16383);
                hq[e] = qv >> 7;
                lq[e] = qv & 127;
            }
            hw[g] = pack_b(hq[0], hq[1], hq[2], hq[3]);
            lw[g] = pack_b(lq[0], lq[1], lq[2], lq[3]);
        }
        *reinterpret_cast<uint4*>(&xh8[0][row][16 * tq]) = make_uint4(hw[0], hw[1], hw[2], hw[3]);
        *reinterpret_cast<uint4*>(&xl8[0][row][16 * tq]) = make_uint4(lw[0], lw[1], lw[2], lw[3]);
    }
    __syncthreads();

    // ---- pass 2: planes 1..7 = plane 0 shifted by S bytes ----
    for (int task = tid; task < 700; task += 256) {
        const int S = 1 + task / 100;          // 1..7
        const int rem = task % 100;
        const int row = rem / 10, tq = rem % 10;   // output cols 16tq..16tq+15 (j<160)
        const int s0 = S >> 2;
        const int sh = (S & 3) * 8;
        shift_plane(&xh8[0][0][0], S, row, tq, s0, sh);
        shift_plane(&xl8[0][0][0], S, row, tq, s0, sh);
    }
    __syncthreads();

    const int L    = tid & 63;
    const int j_p  = tid >> 6;       // wave id = pot row
    const int q    = L >> 4;         // quad: k-group 16q..16q+15
    const int n16  = L & 15;         // A: m-index; B: fm-index

    // per-kk octet-piece geometry (taps tA=64kk+16q, tB=tA+8; never cross a w-row)
    int preA[4], preB[4];
#pragma unroll
    for (int kk = 0; kk < 4; ++kk) {
        const int tA = 64 * kk + 16 * q;
        const int tB = tA + 8;
        const int rA = tA / 40, cA = tA % 40;
        const int rB = tB / 40, cB = tB % 40;
        preA[kk] = (j_p + rA) * 176 + cA + 8 * n16;
        preB[kk] = (j_p + rB) * 176 + cB + 8 * n16;
    }

    unsigned mask = 0;

#pragma unroll 1
    for (int ft = 0; ft < 4; ++ft) {
        const int fm = ft * 16 + n16;
        i32x4 bh[4], bm[4];
        if (PRE) {
            const int fb = (sec * 64 + ft * 16 + n16) * 16 + q;
#pragma unroll
            for (int kk = 0; kk < 4; ++kk) {
                bh[kk] = *reinterpret_cast<const i32x4*>(&wfh[fb + 4 * kk]);
                bm[kk] = *reinterpret_cast<const i32x4*>(&wfm[fb + 4 * kk]);
            }
        } else {
            // fallback: in-kernel quantize (used only if ws too small)
#pragma unroll
            for (int kk = 0; kk < 4; ++kk) {
                const int t0 = 64 * kk + 16 * q;
                unsigned hw[4], mw[4];
#pragma unroll
                for (int g = 0; g < 4; ++g) {
                    int hq[4], mq[4];
#pragma unroll
                    for (int e = 0; e < 4; ++e) {
                        const int t = t0 + 4 * g + e;
                        const bool valid = (t < 240) && (fm < FM);
                        const int fmC = valid ? fm : 0;
                        const int tC  = valid ? t : 0;
                        float w = Wg[((size_t)sec * FM + fmC) * 240 + tC];
                        if (!valid) w = 0.f;
                        quant_w2(w, hq[e], mq[e]);
                    }
                    hw[g] = pack_b(hq[0], hq[1], hq[2], hq[3]);
                    mw[g] = pack_b(mq[0], mq[1], mq[2], mq[3]);
                }
                bh[kk] = (i32x4){(int)hw[0], (int)hw[1], (int)hw[2], (int)hw[3]};
                bm[kk] = (i32x4){(int)mw[0], (int)mw[1], (int)mw[2], (int)mw[3]};
            }
        }

#pragma unroll 1
        for (int res = 0; res < 8; ++res) {
            const unsigned char* hb8 = &xh8[0][0][0] + res * 1760;
            const unsigned char* lb8 = &xl8[0][0][0] + res * 1760;

            i32x4 a1 = {0, 0, 0, 0}, a2 = {0, 0, 0, 0}, a3 = {0, 0, 0, 0};
#pragma unroll
            for (int kk = 0; kk < 4; ++kk) {
                i32x2 hA  = *reinterpret_cast<const i32x2*>(hb8 + preA[kk]);
                i32x2 hBv = *reinterpret_cast<const i32x2*>(hb8 + preB[kk]);
                i32x2 lA  = *reinterpret_cast<const i32x2*>(lb8 + preA[kk]);
                i32x2 lBv = *reinterpret_cast<const i32x2*>(lb8 + preB[kk]);
                i32x4 ah = {hA[0], hA[1], hBv[0], hBv[1]};
                i32x4 al = {lA[0], lA[1], lBv[0], lBv[1]};
                a1 = __builtin_amdgcn_mfma_i32_16x16x64_i8(ah, bh[kk], a1, 0, 0, 0);
                a2 = __builtin_amdgcn_mfma_i32_16x16x64_i8(ah, bm[kk], a2, 0, 0, 0);
                a2 = __builtin_amdgcn_mfma_i32_16x16x64_i8(al, bh[kk], a2, 0, 0, 0);
                a3 = __builtin_amdgcn_mfma_i32_16x16x64_i8(al, bm[kk], a3, 0, 0, 0);
            }

            // ---- epilogue: recombine, repair borderline, set pool bits ----
            // pot = (a1*2^14 + a2*2^7 + a3) * 2^-25
#pragma unroll
            for (int reg = 0; reg < 4; ++reg) {
                const int I = a1[reg] * 128 + a2[reg];     // <= ~5.1e8, fits i32
                float v = fmaf((float)I, 0x1p-18f, (float)a3[reg] * 0x1p-25f);
                const int m   = q * 4 + reg;
                const int pcg = w0 + res + 8 * m;          // global pot col
                const bool valid = (fm < FM) && (pcg <= 2007);
                if (valid && __builtin_fabsf(v - THRESH) < MARGIN) {
                    float pot = 0.f;
#pragma unroll 1
                    for (int r2 = 0; r2 < 6; ++r2) {
                        const float* xr = x + ((size_t)tt * H_ + rowbase + j_p + r2) * WD_ + pcg;
                        const float* wr = Wg + (size_t)sec * FM * 240 + (size_t)fm * 240 + r2 * 40;
#pragma unroll 1
                        for (int c = 0; c < 40; ++c)
                            pot = fmaf(xr[c], wr[c], pot);
                    }
                    v = pot;
                }
                if (v > THRESH)
                    mask |= 1u << (reg * 8 + ft * 2 + (res >> 2));
            }
        }
    }

    lmask[j_p][L] = mask;
    __syncthreads();

    // ---- cross-wave OR + pooled write + fused first-spike argmin ----
    int mykey = 0x7fffffff;
    for (int e = tid; e < 2048; e += 256) {
        const int fmo = e >> 5, p = e & 31;
        const int m = p >> 1, rg = p & 1, ftc = fmo >> 4, fn = fmo & 15;
        const int lane = (m >> 2) * 16 + fn;
        const int bitpos = (m & 3) * 8 + ftc * 2 + rg;
        const unsigned bits = lmask[0][lane] | lmask[1][lane] |
                              lmask[2][lane] | lmask[3][lane];
        const int pg = coltile * 32 + p;
        const int spk = (bits >> bitpos) & 1u;
        if (fmo < FM && pg < WP) {
            out[((size_t)(sec * T_ + tt) * FM + fmo) * WP + pg] = spk ? 1.0f : 0.0f;
            if (spk) mykey = min(mykey, fmo * WP + pg);   // section-flat idx
        }
    }
    red[tid] = mykey;
    __syncthreads();
    for (int s = 128; s > 0; s >>= 1) {
        if (tid < s) red[tid] = min(red[tid], red[tid + s]);
        __syncthreads();
    }
    if (tid == 0 && red[0] != 0x7fffffff)
        atomicMin(&keys[sec], (tt << 15) | red[0]);
}

// ---------------- init (fallback only) ----------------
__global__ void init_kernel(int* __restrict__ ws)
{
    if (threadIdx.x < NSEC) ws[threadIdx.x] = 0x7fffffff;
}

// ---------------- Kernel D: finalize winners ----------------
__global__ void finalize_kernel(const int* __restrict__ ws, float* __restrict__ out)
{
    const int i = threadIdx.x;
    if (i < NSEC) {
        const int key = ws[i];
        float feat;
        if (key == 0x7fffffff) feat = -1.0f;
        else                   feat = (float)((key & 32767) / WP);
        out[POOLED_SIZE + i] = feat;
    }
}

extern "C" void kernel_launch(void* const* d_in, const int* in_sizes, int n_in,
                              void* d_out, int out_size, void* d_ws, size_t ws_size,
                              hipStream_t stream) {
    const float* x  = (const float*)d_in[0];
    const float* Wg = (const float*)d_in[1];
    float* out = (float*)d_out;
    int*   wsi = (int*)d_ws;
    uint4* wfh = (uint4*)((char*)d_ws + 256);
    uint4* wfm = wfh + NFRAG8;

    const bool pre = ws_size >= 256 + (size_t)NFRAG8 * 16 * 2;   // ~295 KB
    if (pre) {
        prep_kernel<<<dim3(36), dim3(256), 0, stream>>>(Wg, wsi, wfh, wfm);
        conv_pool_kernel<true><<<dim3(4320), dim3(256), 0, stream>>>(x, Wg, wfh, wfm, out, wsi);
    } else {
        init_kernel<<<dim3(1), dim3(64), 0, stream>>>(wsi);
        conv_pool_kernel<false><<<dim3(4320), dim3(256), 0, stream>>>(x, Wg, wfh, wfm, out, wsi);
    }
    finalize_kernel<<<dim3(1), dim3(16), 0, stream>>>(wsi, out);
}

// Round 4
// 349.001 us; speedup vs baseline: 1.3094x; 1.3094x over previous
//
#include <hip/hip_runtime.h>

#define T_ 30
#define H_ 41
#define WD_ 2048
#define NSEC 9
#define FM 50
#define WP 502
#define THRESH 23.0f
#define POOLED_SIZE (NSEC * T_ * FM * WP)   // 6,777,000
#define MARGIN 0.0078125f                   // 2^-7 >= worst-case bf16-split error
#define NFRAG 18432                         // 9 sec * 64 fm * 32 tap-octets

typedef short short8 __attribute__((ext_vector_type(8)));
typedef short short4v __attribute__((ext_vector_type(4)));
typedef float f32x4 __attribute__((ext_vector_type(4)));

__device__ __forceinline__ unsigned bf16_rne(float f) {
    unsigned u = __float_as_uint(f);
    return (u + 0x7fffu + ((u >> 16) & 1u)) >> 16;
}

// ---------------- prep: W -> MFMA-ready bf16 hi/lo fragments in ws --------
__global__ __launch_bounds__(256) void prep_kernel(
    const float* __restrict__ Wg, int* __restrict__ wsi,
    uint4* __restrict__ wfh, uint4* __restrict__ wfl)
{
    const int gid = blockIdx.x * 256 + threadIdx.x;
    if (gid < NSEC) wsi[gid] = 0x7fffffff;
    if (gid >= NFRAG) return;
    const int blk = gid & 31;
    const int fm  = (gid >> 5) & 63;
    const int sec = gid >> 11;
    const int t0  = blk * 8;
    const bool valid = (t0 < 240) && (fm < FM);
    unsigned hh[4], ll[4];
    const float* wp = Wg + ((size_t)sec * FM + (valid ? fm : 0)) * 240 + (valid ? t0 : 0);
    float4 wa = *reinterpret_cast<const float4*>(wp);
    float4 wb = *reinterpret_cast<const float4*>(wp + 4);
    float f[8] = {wa.x, wa.y, wa.z, wa.w, wb.x, wb.y, wb.z, wb.w};
#pragma unroll
    for (int i = 0; i < 4; ++i) {
        float f0 = valid ? f[2 * i] : 0.f;
        float f1 = valid ? f[2 * i + 1] : 0.f;
        unsigned h0 = bf16_rne(f0), h1 = bf16_rne(f1);
        float hf0 = __uint_as_float(h0 << 16), hf1 = __uint_as_float(h1 << 16);
        unsigned l0 = bf16_rne(f0 - hf0), l1 = bf16_rne(f1 - hf1);
        hh[i] = (h1 << 16) | h0;
        ll[i] = (l1 << 16) | l0;
    }
    wfh[gid] = *reinterpret_cast<uint4*>(hh);
    wfl[gid] = *reinterpret_cast<uint4*>(ll);
}

// ---------------- Kernel A: split-bf16 MFMA conv + fire + pool + argmin ----
// R13 == R12 with the acc1 split-term bug fixed (third MFMA: ah1*wl, was
// al1*wl). Structure vs R8 (322us baseline):
//  (1) res-pair ILP: res=S (off0) and res=S+4 (off4) computed together ->
//      two independent 24-MFMA accumulator chains sharing weight regs.
//      Split terms per chain: ah*wh + al*wh + ah*wl  (drop al*wl, < 2^-14).
//  (2) XOR bank swizzle: rows padded 176->192 elems; elem col ^= (row&7)<<3
//      on write AND read. Bijective within each 64-elem aligned block; all
//      reads stay 8-slot-aligned (c0, 8*n16 multiples of 8; +4 sub-offset
//      commutes with the XOR since xr is a multiple of 8).
//  (3) lmask/red union (1KB) -> LDS 31744B -> up to 5 blocks/CU.
template <bool PRE>
__global__ __launch_bounds__(256) void conv_pool_kernel(
    const float* __restrict__ x, const float* __restrict__ Wg,
    const uint4* __restrict__ wfh, const uint4* __restrict__ wfl,
    float* __restrict__ out, int* __restrict__ keys)
{
    __shared__ __align__(16) unsigned short xh[4][10][192];   // 15 KB
    __shared__ __align__(16) unsigned short xl[4][10][192];   // 15 KB
    __shared__ int sred[256];                                  // lmask, then red

    const int b       = blockIdx.x;
    const int coltile = b & 15;
    const int tt      = (b >> 4) % T_;
    const int sec     = b / 480;
    const int w0      = coltile * 128;     // pot-col base
    const int rowbase = 4 * sec;
    const int tid     = threadIdx.x;

    // ---- stage x: 10 rows x 176 cols -> hi/lo u16, 4 shifted copies, swizzled ----
    for (int i = tid; i < 440; i += 256) {
        const int row = i / 44;
        const int c4  = i % 44;
        const int grow = (rowbase + row < H_) ? rowbase + row : H_ - 1;
        const int gc   = w0 + 4 * c4;
        float4 v;
        if (gc + 3 < WD_) {
            v = *reinterpret_cast<const float4*>(x + ((size_t)tt * H_ + grow) * WD_ + gc);
        } else {
            v.x = v.y = v.z = v.w = 0.f;
        }
        float f[4] = {v.x, v.y, v.z, v.w};
        unsigned short hq[4], lq[4];
#pragma unroll
        for (int e = 0; e < 4; ++e) {
            unsigned h = bf16_rne(f[e]);
            float hf = __uint_as_float(h << 16);
            unsigned l = bf16_rne(f[e] - hf);
            hq[e] = (unsigned short)h;
            lq[e] = (unsigned short)l;
        }
        const int xr = (row & 7) << 3;
#pragma unroll
        for (int S = 0; S < 4; ++S)
#pragma unroll
            for (int e = 0; e < 4; ++e) {
                const int j = 4 * c4 + e - S;
                if (j >= 0 && j < 176) {
                    xh[S][row][j ^ xr] = hq[e];
                    xl[S][row][j ^ xr] = lq[e];
                }
            }
    }
    __syncthreads();

    const int L    = tid & 63;
    const int j_p  = tid >> 6;       // wave id = pot row
    const int q    = L >> 4;         // quad
    const int n16  = L & 15;         // A: m-index; B: fm-index

    // per-kk tap geometry (tau0 = 32kk + 8q -> weight row r, col c0), swizzled
    int pA[8], pB[8];
#pragma unroll
    for (int kk = 0; kk < 8; ++kk) {
        const int t0 = 32 * kk + 8 * q;
        const int r  = t0 / 40;
        const int c0 = t0 - 40 * r;          // multiple of 8
        const int row = j_p + r;
        const int xr  = (row & 7) << 3;
        const int s   = c0 + 8 * n16;        // multiple of 8, <= 152
        pA[kk] = row * 192 + (s ^ xr);       // slot [s, s+8)
        pB[kk] = row * 192 + ((s + 8) ^ xr); // slot [s+8, s+16)
    }

    unsigned mask = 0;

#pragma unroll 1
    for (int ft = 0; ft < 4; ++ft) {
        const int fm = ft * 16 + n16;
        short8 wh[8], wl[8];
        if (PRE) {
            const int fb = (sec * 64 + ft * 16 + n16) * 32 + q;
#pragma unroll
            for (int kk = 0; kk < 8; ++kk) {
                uint4 hu = wfh[fb + 4 * kk];
                uint4 lu = wfl[fb + 4 * kk];
                union { uint4 u; short8 s; } c1, c2;
                c1.u = hu; c2.u = lu;
                wh[kk] = c1.s; wl[kk] = c2.s;
            }
        } else {
            // fallback: in-kernel build (used only if ws too small)
#pragma unroll
            for (int kk = 0; kk < 8; ++kk) {
                const int t0 = 32 * kk + 8 * q;
                const bool wvalid = (t0 < 240) && (fm < FM);
                const float* wp = Wg + (size_t)sec * FM * 240 +
                                  (size_t)(wvalid ? fm : 0) * 240 + (wvalid ? t0 : 0);
                float4 wa = *reinterpret_cast<const float4*>(wp);
                float4 wb = *reinterpret_cast<const float4*>(wp + 4);
                float f[8] = {wa.x, wa.y, wa.z, wa.w, wb.x, wb.y, wb.z, wb.w};
                unsigned hh[4], ll[4];
#pragma unroll
                for (int i = 0; i < 4; ++i) {
                    float f0 = wvalid ? f[2 * i] : 0.f;
                    float f1 = wvalid ? f[2 * i + 1] : 0.f;
                    unsigned h0 = bf16_rne(f0), h1 = bf16_rne(f1);
                    float hf0 = __uint_as_float(h0 << 16), hf1 = __uint_as_float(h1 << 16);
                    unsigned l0 = bf16_rne(f0 - hf0), l1 = bf16_rne(f1 - hf1);
                    hh[i] = (h1 << 16) | h0;
                    ll[i] = (l1 << 16) | l0;
                }
                wh[kk] = *reinterpret_cast<short8*>(hh);
                wl[kk] = *reinterpret_cast<short8*>(ll);
            }
        }

#pragma unroll 1
        for (int S = 0; S < 4; ++S) {
            const unsigned short* hb = &xh[S][0][0];
            const unsigned short* lb = &xl[S][0][0];

            f32x4 acc0 = {0.f, 0.f, 0.f, 0.f};   // res = S     (off 0)
            f32x4 acc1 = {0.f, 0.f, 0.f, 0.f};   // res = S + 4 (off 4)
#pragma unroll
            for (int kk = 0; kk < 8; ++kk) {
                short8 ah0 = *reinterpret_cast<const short8*>(hb + pA[kk]);
                short8 al0 = *reinterpret_cast<const short8*>(lb + pA[kk]);
                short4v h0 = *reinterpret_cast<const short4v*>(hb + pA[kk] + 4);
                short4v h1 = *reinterpret_cast<const short4v*>(hb + pB[kk]);
                short4v l0 = *reinterpret_cast<const short4v*>(lb + pA[kk] + 4);
                short4v l1 = *reinterpret_cast<const short4v*>(lb + pB[kk]);
                short8 ah1 = __builtin_shufflevector(h0, h1, 0, 1, 2, 3, 4, 5, 6, 7);
                short8 al1 = __builtin_shufflevector(l0, l1, 0, 1, 2, 3, 4, 5, 6, 7);
                acc0 = __builtin_amdgcn_mfma_f32_16x16x32_bf16(ah0, wh[kk], acc0, 0, 0, 0);
                acc1 = __builtin_amdgcn_mfma_f32_16x16x32_bf16(ah1, wh[kk], acc1, 0, 0, 0);
                acc0 = __builtin_amdgcn_mfma_f32_16x16x32_bf16(al0, wh[kk], acc0, 0, 0, 0);
                acc1 = __builtin_amdgcn_mfma_f32_16x16x32_bf16(al1, wh[kk], acc1, 0, 0, 0);
                acc0 = __builtin_amdgcn_mfma_f32_16x16x32_bf16(ah0, wl[kk], acc0, 0, 0, 0);
                acc1 = __builtin_amdgcn_mfma_f32_16x16x32_bf16(ah1, wl[kk], acc1, 0, 0, 0);
            }

            // ---- epilogue: repair borderline, set pool bits (both res) ----
            auto epilogue = [&](const f32x4& acc, const int res) {
#pragma unroll
                for (int reg = 0; reg < 4; ++reg) {
                    float v = acc[reg];
                    const int m   = q * 4 + reg;
                    const int pcg = w0 + res + 8 * m;     // global pot col
                    const bool valid = (fm < FM) && (pcg <= 2007);
                    if (valid && __builtin_fabsf(v - THRESH) < MARGIN) {
                        float pot = 0.f;
#pragma unroll 1
                        for (int r2 = 0; r2 < 6; ++r2) {
                            const float* xr2 = x + ((size_t)tt * H_ + rowbase + j_p + r2) * WD_ + pcg;
                            const float* wr = Wg + (size_t)sec * FM * 240 + (size_t)fm * 240 + r2 * 40;
#pragma unroll 1
                            for (int c = 0; c < 40; ++c)
                                pot = fmaf(xr2[c], wr[c], pot);
                        }
                        v = pot;
                    }
                    if (v > THRESH)
                        mask |= 1u << (reg * 8 + ft * 2 + (res >> 2));
                }
            };
            epilogue(acc0, S);
            epilogue(acc1, S + 4);
        }
    }

    unsigned* lmask = reinterpret_cast<unsigned*>(sred);
    lmask[j_p * 64 + L] = mask;
    __syncthreads();

    // ---- cross-wave OR + pooled write + fused first-spike argmin ----
    int mykey = 0x7fffffff;
    for (int e = tid; e < 2048; e += 256) {
        const int fmo = e >> 5, p = e & 31;
        const int m = p >> 1, rg = p & 1, ftc = fmo >> 4, fn = fmo & 15;
        const int lane = (m >> 2) * 16 + fn;
        const int bitpos = (m & 3) * 8 + ftc * 2 + rg;
        const unsigned bits = lmask[0 * 64 + lane] | lmask[1 * 64 + lane] |
                              lmask[2 * 64 + lane] | lmask[3 * 64 + lane];
        const int pg = coltile * 32 + p;
        const int spk = (bits >> bitpos) & 1u;
        if (fmo < FM && pg < WP) {
            out[((size_t)(sec * T_ + tt) * FM + fmo) * WP + pg] = spk ? 1.0f : 0.0f;
            if (spk) mykey = min(mykey, fmo * WP + pg);   // section-flat idx
        }
    }
    __syncthreads();                     // protect lmask -> red reuse
    sred[tid] = mykey;
    __syncthreads();
    for (int s = 128; s > 0; s >>= 1) {
        if (tid < s) sred[tid] = min(sred[tid], sred[tid + s]);
        __syncthreads();
    }
    if (tid == 0 && sred[0] != 0x7fffffff)
        atomicMin(&keys[sec], (tt << 15) | sred[0]);
}

// ---------------- init (fallback only) ----------------
__global__ void init_kernel(int* __restrict__ ws)
{
    if (threadIdx.x < NSEC) ws[threadIdx.x] = 0x7fffffff;
}

// ---------------- Kernel D: finalize winners ----------------
__global__ void finalize_kernel(const int* __restrict__ ws, float* __restrict__ out)
{
    const int i = threadIdx.x;
    if (i < NSEC) {
        const int key = ws[i];
        float feat;
        if (key == 0x7fffffff) feat = -1.0f;
        else                   feat = (float)((key & 32767) / WP);
        out[POOLED_SIZE + i] = feat;
    }
}

extern "C" void kernel_launch(void* const* d_in, const int* in_sizes, int n_in,
                              void* d_out, int out_size, void* d_ws, size_t ws_size,
                              hipStream_t stream) {
    const float* x  = (const float*)d_in[0];
    const float* Wg = (const float*)d_in[1];
    float* out = (float*)d_out;
    int*   wsi = (int*)d_ws;
    uint4* wfh = (uint4*)((char*)d_ws + 256);
    uint4* wfl = wfh + NFRAG;

    const bool pre = ws_size >= 256 + (size_t)NFRAG * 16 * 2;   // 590 KB
    if (pre) {
        prep_kernel<<<dim3(72), dim3(256), 0, stream>>>(Wg, wsi, wfh, wfl);
        conv_pool_kernel<true><<<dim3(4320), dim3(256), 0, stream>>>(x, Wg, wfh, wfl, out, wsi);
    } else {
        init_kernel<<<dim3(1), dim3(64), 0, stream>>>(wsi);
        conv_pool_kernel<false><<<dim3(4320), dim3(256), 0, stream>>>(x, Wg, wfh, wfl, out, wsi);
    }
    finalize_kernel<<<dim3(1), dim3(16), 0, stream>>>(wsi, out);
}